// Round 9
// baseline (281.566 us; speedup 1.0000x reference)
//
#include <hip/hip_runtime.h>
#include <hip/hip_bf16.h>

#define G 160
#define GM1 159
#define KD 128    // 16 k * 8 d complex channels
#define KP 320    // doubled K (re/im interleaved)
#define PLANE_U 3276800   // uints per plane of B/T (128*160*160)
#define NBUCK 4096        // 2^12 morton buckets (4 bits/axis)
#define TWO_PI_F 6.28318530717958647692f

typedef __attribute__((ext_vector_type(8))) short bf16x8;   // 4 VGPRs, 8 bf16
typedef __attribute__((ext_vector_type(4))) float f32x4;

__device__ __forceinline__ unsigned short f2bf(float x) {
    unsigned u = __float_as_uint(x);
    unsigned r = (u + 0x7FFFu + ((u >> 16) & 1u)) >> 16;   // RNE
    return (unsigned short)r;
}
__device__ __forceinline__ unsigned int packbf(float re, float im) {
    union { __hip_bfloat162 h; unsigned int u; } cv;
    cv.h = __float22bfloat162_rn(make_float2(re, im));      // v_cvt_pk_bf16_f32
    return cv.u;
}
__device__ __forceinline__ float bfl(unsigned u) { return __uint_as_float(u << 16); }
__device__ __forceinline__ float bfh(unsigned u) { return __uint_as_float(u & 0xffff0000u); }
// Wim fragment uint from Wre fragment uint: (c,-s) -> (s,c)
__device__ __forceinline__ unsigned int wim_of(unsigned int u) {
    return ((u << 16) | (u >> 16)) ^ 0x00008000u;
}
__device__ __forceinline__ unsigned part1by2(unsigned x) {
    x &= 0x3FF;
    x = (x | (x << 16)) & 0xFF0000FFu;
    x = (x | (x << 8))  & 0x0300F00Fu;
    x = (x | (x << 4))  & 0x030C30C3u;
    x = (x | (x << 2))  & 0x09249249u;
    return x;
}
__device__ __forceinline__ unsigned morton_key(float x, float y, float z) {
    int cx = min(max((int)((x + 1.0f) * 8.0f), 0), 15);
    int cy = min(max((int)((y + 1.0f) * 8.0f), 0), 15);
    int cz = min(max((int)((z + 1.0f) * 8.0f), 0), 15);
    return part1by2(cx) | (part1by2(cy) << 1) | (part1by2(cz) << 2);   // 12 bits
}

// ---------------------------------------------------------------------------
// Fused preprocessing: [0,16) zero counts | [16,216) W init | [216,1816) packw
// ---------------------------------------------------------------------------
__global__ __launch_bounds__(256) void k_prep(
    const float* __restrict__ Pw_re, const float* __restrict__ Pw_im,
    unsigned int* __restrict__ Apw, unsigned short* __restrict__ Wre,
    unsigned int* __restrict__ counts)
{
    __shared__ unsigned int sT[64 * 33];
    int b = blockIdx.x;
    int tid = threadIdx.x;
    if (b < 16) {
        counts[b * 256 + tid] = 0;
        return;
    }
    if (b < 216) {
        int idx = (b - 16) * 256 + tid;   // < 51200
        int r = idx / KP, kp = idx - r * KP;
        int q = kp >> 1;
        int m = (r * q) % G;
        float th = (float)m * (TWO_PI_F / (float)G);
        float s, c;
        __sincosf(th, &s, &c);
        Wre[idx] = f2bf(((kp & 1) == 0 ? c : -s) * (1.0f / (float)G));
        return;
    }
    // packw: Pw (k,y,x,d) [204800, 8, 1280, 1] -> Apw[m=(k*8+d)*160+y][q=x]
    int b2 = b - 216;                     // 0..1599
    int k  = b2 / 100;
    int rem = b2 - k * 100;
    int pc = rem / 5;
    int q0 = (rem - pc * 5) * 32;

    int i = tid & 63, qo = tid >> 6;
    size_t base = (size_t)k * 204800 + (size_t)pc * 64 + i;
    #pragma unroll
    for (int qc = 0; qc < 8; qc++) {
        int q = q0 + qo * 8 + qc;
        float r  = Pw_re[base + (size_t)q * 1280];
        float im = Pw_im[base + (size_t)q * 1280];
        sT[i * 33 + qo * 8 + qc] = packbf(r, im);
    }
    __syncthreads();
    int qp = tid & 31, mo = tid >> 5;
    #pragma unroll
    for (int mc = 0; mc < 8; mc++) {
        int m = (k * 8 + mo) * G + pc * 8 + mc;
        Apw[(size_t)m * G + q0 + qp] = sT[(mc * 8 + mo) * 33 + qp];
    }
}

// ---------------------------------------------------------------------------
// Morton counting sort: hist -> scan -> scatter(sorted float4)
// ---------------------------------------------------------------------------
__global__ __launch_bounds__(256) void k_hist(
    const float* __restrict__ xyz, const float* __restrict__ bound,
    unsigned int* __restrict__ counts, int N)
{
    int i = blockIdx.x * blockDim.x + threadIdx.x;
    if (i >= N) return;
    float invb = 1.0f / bound[0];
    float x = xyz[3 * i + 0] * invb;
    float y = xyz[3 * i + 1] * invb;
    float z = xyz[3 * i + 2] * invb;
    atomicAdd(&counts[morton_key(x, y, z)], 1u);
}

__global__ __launch_bounds__(1024) void k_scan(
    const unsigned int* __restrict__ counts,
    unsigned int* __restrict__ cursors)
{
    __shared__ unsigned int sT[1024];
    int t = threadIdx.x;
    unsigned int local[4];
    unsigned int s = 0;
    #pragma unroll
    for (int i = 0; i < 4; i++) { local[i] = counts[t * 4 + i]; s += local[i]; }
    sT[t] = s;
    __syncthreads();
    for (int off = 1; off < 1024; off <<= 1) {
        unsigned int v = (t >= off) ? sT[t - off] : 0u;
        __syncthreads();
        sT[t] += v;
        __syncthreads();
    }
    unsigned int run = (t > 0) ? sT[t - 1] : 0u;
    #pragma unroll
    for (int i = 0; i < 4; i++) { cursors[t * 4 + i] = run; run += local[i]; }
}

__global__ __launch_bounds__(256) void k_scatter(
    const float* __restrict__ xyz, const float* __restrict__ bound,
    unsigned int* __restrict__ cursors, float4* __restrict__ sxyz, int N)
{
    int i = blockIdx.x * blockDim.x + threadIdx.x;
    if (i >= N) return;
    float invb = 1.0f / bound[0];
    float x = xyz[3 * i + 0] * invb;
    float y = xyz[3 * i + 1] * invb;
    float z = xyz[3 * i + 2] * invb;
    unsigned int pos = atomicAdd(&cursors[morton_key(x, y, z)], 1u);
    sxyz[pos] = make_float4(x, y, z, __int_as_float(i));
}

// ---------------------------------------------------------------------------
// Stage 1: B[m=(kd,p)][l] = alpha * sum_q A*W[l][q].  Wave = ONE m-tile
// (A-frags in registers) -> 3840 waves (15/CU) for latency hiding.
// W streamed from L2 (br only, bi derived). Output in MFMA B-frag order.
// ---------------------------------------------------------------------------
__global__ __launch_bounds__(512) void k_stage1(
    const float* __restrict__ Pu_re, const float* __restrict__ Pu_im,
    const float* __restrict__ Pv_re, const float* __restrict__ Pv_im,
    const unsigned int* __restrict__ Apw,
    const float* __restrict__ alpha_params,
    const unsigned short* __restrict__ Wre,
    unsigned int* __restrict__ Bfrag)
{
    int tid = threadIdx.x;
    int w = tid >> 6, lane = tid & 63;
    int col = lane & 15, g4 = lane >> 4;
    int gw = blockIdx.x * 8 + w;          // 0..3839 wave-tasks (one m-tile each)
    int plane = gw / 1280;
    int mtl = gw - plane * 1280;

    float ap = alpha_params[0];
    float bxv = 10.0f * ap;
    float alpha = (bxv > 1.0f) ? ap : log1pf(expf(fminf(bxv, 1.0f))) * 0.1f;

    bf16x8 afr[10];
    if (plane == 2) {
        const unsigned int* a2 = Apw + (size_t)(mtl * 16 + col) * G + g4 * 4;
        #pragma unroll
        for (int t = 0; t < 10; t++) {
            union { uint4 u; bf16x8 b; } cv;
            cv.u = *(const uint4*)(a2 + t * 16);
            afr[t] = cv.b;
        }
    } else {
        const float *Ar, *Ai; int sd_, sp_;
        if (plane == 0) { Ar = Pu_re; Ai = Pu_im; sd_ = 25600; sp_ = 160; }
        else            { Ar = Pv_re; Ai = Pv_im; sd_ = 160;   sp_ = 1280; }
        int m = mtl * 16 + col;
        int k = m / 1280; int rm = m - k * 1280;
        int d = rm / 160; int p = rm - d * 160;
        size_t abase = (size_t)k * 204800 + (size_t)d * sd_ + (size_t)p * sp_ + g4 * 4;
        #pragma unroll
        for (int t = 0; t < 10; t++) {
            float4 vr = *(const float4*)(Ar + abase + t * 16);
            float4 vi = *(const float4*)(Ai + abase + t * 16);
            union { unsigned int u[4]; bf16x8 b; } cv;
            cv.u[0] = packbf(vr.x, vi.x); cv.u[1] = packbf(vr.y, vi.y);
            cv.u[2] = packbf(vr.z, vi.z); cv.u[3] = packbf(vr.w, vi.w);
            afr[t] = cv.b;
        }
    }

    unsigned int* Bpl = Bfrag + (size_t)plane * PLANE_U;
    int kd = mtl / 10, pt = mtl - kd * 10;

    for (int lt = 0; lt < 10; lt++) {
        f32x4 ar = (f32x4)(0.f), ai = (f32x4)(0.f);
        const unsigned short* wp = &Wre[(lt * 16 + col) * KP + g4 * 8];
        #pragma unroll
        for (int t = 0; t < 10; t++) {
            union { uint4 u; bf16x8 b; } cr, ci;
            cr.u = *(const uint4*)(wp + t * 32);
            ci.u.x = wim_of(cr.u.x); ci.u.y = wim_of(cr.u.y);
            ci.u.z = wim_of(cr.u.z); ci.u.w = wim_of(cr.u.w);
            ar = __builtin_amdgcn_mfma_f32_16x16x32_bf16(afr[t], cr.b, ar, 0, 0, 0);
            ai = __builtin_amdgcn_mfma_f32_16x16x32_bf16(afr[t], ci.b, ai, 0, 0, 0);
        }
        uint4 o;
        o.x = packbf(alpha * ar[0], alpha * ai[0]);
        o.y = packbf(alpha * ar[1], alpha * ai[1]);
        o.z = packbf(alpha * ar[2], alpha * ai[2]);
        o.w = packbf(alpha * ar[3], alpha * ai[3]);
        *(uint4*)(Bpl + (size_t)(kd * 10 + lt) * 2560 + pt * 256 + lane * 4) = o;
    }
}

// ---------------------------------------------------------------------------
// Stage 2: T[j][l][kd] = sum_p W[j][p]*B[kd][p][l].
// Block = (kd-octet, l-tile, plane), 640 thr = 10 waves = 10 j-tiles.
// B octet staged once into 80KB LDS; W A-frags register-hoisted.
// ---------------------------------------------------------------------------
__global__ __launch_bounds__(640) void k_stage2(
    const unsigned int* __restrict__ Bfrag,
    const unsigned short* __restrict__ Wre,
    unsigned int* __restrict__ Tall)
{
    __shared__ __align__(16) unsigned int sB[20480];   // 80 KB: 8 kd x 2560
    int tid = threadIdx.x;
    int w = tid >> 6, lane = tid & 63;
    int col = lane & 15, g4 = lane >> 4;
    int kdo = blockIdx.x;
    int lt  = blockIdx.y;
    int plane = blockIdx.z;

    const unsigned int* Bp = Bfrag + (size_t)plane * PLANE_U;
    #pragma unroll
    for (int i = 0; i < 8; i++) {
        uint4 v = *(const uint4*)(Bp + ((size_t)(kdo * 8 + i) * 10 + lt) * 2560 + tid * 4);
        *(uint4*)(sB + i * 2560 + tid * 4) = v;
    }

    bf16x8 wfr[10];
    const unsigned short* wp = &Wre[(w * 16 + col) * KP + g4 * 8];
    #pragma unroll
    for (int t = 0; t < 10; t++)
        wfr[t] = *(const bf16x8*)(wp + t * 32);

    __syncthreads();

    f32x4 ar[8], ai[8];
    #pragma unroll
    for (int i = 0; i < 8; i++) { ar[i] = (f32x4)(0.f); ai[i] = (f32x4)(0.f); }

    #pragma unroll
    for (int t = 0; t < 10; t++) {
        union { bf16x8 b; uint4 u; } cr, ci;
        cr.b = wfr[t];
        ci.u.x = wim_of(cr.u.x); ci.u.y = wim_of(cr.u.y);
        ci.u.z = wim_of(cr.u.z); ci.u.w = wim_of(cr.u.w);
        #pragma unroll
        for (int kq = 0; kq < 8; kq++) {
            bf16x8 bf = *(const bf16x8*)&sB[kq * 2560 + (t * 64 + lane) * 4];
            ar[kq] = __builtin_amdgcn_mfma_f32_16x16x32_bf16(cr.b, bf, ar[kq], 0, 0, 0);
            ai[kq] = __builtin_amdgcn_mfma_f32_16x16x32_bf16(ci.b, bf, ai[kq], 0, 0, 0);
        }
    }

    unsigned int* Tp = Tall + (size_t)plane * PLANE_U;
    #pragma unroll
    for (int reg = 0; reg < 4; reg++) {
        int j = w * 16 + g4 * 4 + reg;
        int l = lt * 16 + col;
        uint4 o0, o1;
        o0.x = packbf(ar[0][reg], ai[0][reg]);
        o0.y = packbf(ar[1][reg], ai[1][reg]);
        o0.z = packbf(ar[2][reg], ai[2][reg]);
        o0.w = packbf(ar[3][reg], ai[3][reg]);
        o1.x = packbf(ar[4][reg], ai[4][reg]);
        o1.y = packbf(ar[5][reg], ai[5][reg]);
        o1.z = packbf(ar[6][reg], ai[6][reg]);
        o1.w = packbf(ar[7][reg], ai[7][reg]);
        size_t ta = ((size_t)(j * G + l)) * KD + kdo * 8;
        *(uint4*)(Tp + ta)     = o0;
        *(uint4*)(Tp + ta + 4) = o1;
    }
}

// ---------------------------------------------------------------------------
// Sampler: 16 lanes/point, lane = k. Phase-split: all 3 planes' addresses,
// all 24 uint4 loads in flight, then f32 unpack math (PROVEN R7 path).
// ---------------------------------------------------------------------------
__device__ __forceinline__ void plane_addr(const unsigned int* __restrict__ T,
    float gy, float gx, int k, const unsigned int** cp, float* wv)
{
    float iy = (gy + 1.0f) * (0.5f * (float)GM1);
    float ix = (gx + 1.0f) * (0.5f * (float)GM1);
    float iy0f = floorf(iy), ix0f = floorf(ix);
    float wy = iy - iy0f, wx = ix - ix0f;
    int iy0 = (int)iy0f, ix0 = (int)ix0f;
    int iy1 = min(iy0 + 1, GM1), ix1 = min(ix0 + 1, GM1);
    iy0 = max(min(iy0, GM1), 0); ix0 = max(min(ix0, GM1), 0);
    iy1 = max(iy1, 0); ix1 = max(ix1, 0);
    cp[0] = &T[(size_t)(iy0 * G + ix0) * KD + k * 8];
    cp[1] = &T[(size_t)(iy0 * G + ix1) * KD + k * 8];
    cp[2] = &T[(size_t)(iy1 * G + ix0) * KD + k * 8];
    cp[3] = &T[(size_t)(iy1 * G + ix1) * KD + k * 8];
    wv[0] = (1.f - wx) * (1.f - wy);
    wv[1] = wx * (1.f - wy);
    wv[2] = (1.f - wx) * wy;
    wv[3] = wx * wy;
}

__device__ __forceinline__ float plane_math(const uint4* va, const uint4* vb,
                                            const float* wv, float fc)
{
    float w00 = wv[0], w01 = wv[1], w10 = wv[2], w11 = wv[3];
    float s1v, c1v;
    __sincosf(TWO_PI_F * fc, &s1v, &c1v);
    float cd[8], sd[8];
    cd[1] = c1v; sd[1] = s1v;
    #pragma unroll
    for (int d = 2; d < 8; d++) {
        float t2 = cd[d - 1] + cd[d - 1];
        cd[d] = __builtin_fmaf(t2, cd[d - 1], -1.0f);
        sd[d] = t2 * sd[d - 1];
    }
    float acc = 0.f;
#define TERM(u0, u1, u2, u3, C, S) { \
    float re = bfl(u0) * w00 + bfl(u1) * w01 + bfl(u2) * w10 + bfl(u3) * w11; \
    float im = bfh(u0) * w00 + bfh(u1) * w01 + bfh(u2) * w10 + bfh(u3) * w11; \
    acc += re * (C) - im * (S); }
    TERM(va[0].x, va[1].x, va[2].x, va[3].x, 1.0f, 0.0f)
    TERM(va[0].y, va[1].y, va[2].y, va[3].y, cd[1] + cd[1], sd[1] + sd[1])
    TERM(va[0].z, va[1].z, va[2].z, va[3].z, cd[2] + cd[2], sd[2] + sd[2])
    TERM(va[0].w, va[1].w, va[2].w, va[3].w, cd[3] + cd[3], sd[3] + sd[3])
    TERM(vb[0].x, vb[1].x, vb[2].x, vb[3].x, cd[4] + cd[4], sd[4] + sd[4])
    TERM(vb[0].y, vb[1].y, vb[2].y, vb[3].y, cd[5] + cd[5], sd[5] + sd[5])
    TERM(vb[0].z, vb[1].z, vb[2].z, vb[3].z, cd[6] + cd[6], sd[6] + sd[6])
    TERM(vb[0].w, vb[1].w, vb[2].w, vb[3].w, cd[7] + cd[7], sd[7] + sd[7])
#undef TERM
    return acc;
}

__global__ __launch_bounds__(256, 3) void k_sample(
    const float4* __restrict__ sxyz,
    const unsigned int* __restrict__ Tu, const unsigned int* __restrict__ Tv,
    const unsigned int* __restrict__ Tw,
    float* __restrict__ out, int N)
{
    int tid = threadIdx.x;
    int k = tid & 15;
    int nblocks = (N + 15) / 16;
    int seg = blockIdx.x & 7;
    int segblocks = nblocks >> 3;                 // N multiple of 128
    int pid = (seg * segblocks + (blockIdx.x >> 3)) * 16 + (tid >> 4);
    if (pid >= N) return;

    float4 pw = sxyz[pid];
    int n = __float_as_int(pw.w);
    float x = pw.x, y = pw.y, z = pw.z;

    const unsigned int* cp[3][4];
    float wv[3][4];
    plane_addr(Tu, y, z, k, cp[0], wv[0]);
    plane_addr(Tv, x, z, k, cp[1], wv[1]);
    plane_addr(Tw, y, x, k, cp[2], wv[2]);

    uint4 va[3][4], vb[3][4];
    #pragma unroll
    for (int pl = 0; pl < 3; pl++)
        #pragma unroll
        for (int c = 0; c < 4; c++) {
            va[pl][c] = *(const uint4*)cp[pl][c];
            vb[pl][c] = *(const uint4*)(cp[pl][c] + 4);
        }

    float acc = plane_math(va[0], vb[0], wv[0], (x + 1.0f) * 0.5f)
              + plane_math(va[1], vb[1], wv[1], (y + 1.0f) * 0.5f)
              + plane_math(va[2], vb[2], wv[2], (z + 1.0f) * 0.5f);
    out[n * 16 + k] = acc;
}

// ---------------------------------------------------------------------------
extern "C" void kernel_launch(void* const* d_in, const int* in_sizes, int n_in,
                              void* d_out, int out_size, void* d_ws, size_t ws_size,
                              hipStream_t stream) {
    const float* xyz          = (const float*)d_in[0];
    const float* bound        = (const float*)d_in[1];
    const float* alpha_params = (const float*)d_in[2];
    const float* Pu_re = (const float*)d_in[3];
    const float* Pu_im = (const float*)d_in[4];
    const float* Pv_re = (const float*)d_in[5];
    const float* Pv_im = (const float*)d_in[6];
    const float* Pw_re = (const float*)d_in[7];
    const float* Pw_im = (const float*)d_in[8];
    float* out = (float*)d_out;
    int N = in_sizes[0] / 3;

    // ws: Wre 100K | Apw 12.5M | Bfrag 37.5M | T 37.5M | counts 16K |
    //     cursors 16K | sxyz 2M
    char* ws = (char*)d_ws;
    unsigned short* Wre  = (unsigned short*)(ws);
    unsigned int*   Apw  = (unsigned int*)(ws + 102400);
    unsigned int*   Bfr  = (unsigned int*)(ws + 102400 + 13107200);
    unsigned int*   Tall = (unsigned int*)(ws + 102400 + 13107200 + 39321600);
    char*           ws2  = ws + 102400 + 13107200 + 39321600 + 39321600;
    unsigned int*   counts  = (unsigned int*)(ws2);
    unsigned int*   cursors = (unsigned int*)(ws2 + 16384);
    float4*         sxyz    = (float4*)(ws2 + 32768);
    unsigned int*   Tu   = Tall;
    unsigned int*   Tv   = Tall + (size_t)PLANE_U;
    unsigned int*   Tw   = Tall + (size_t)2 * PLANE_U;

    // fused prep: zero counts + W table + Pw pack
    k_prep<<<1816, 256, 0, stream>>>(Pw_re, Pw_im, Apw, Wre, counts);
    // sort chain
    k_hist<<<(N + 255) / 256, 256, 0, stream>>>(xyz, bound, counts, N);
    k_scan<<<1, 1024, 0, stream>>>(counts, cursors);
    k_scatter<<<(N + 255) / 256, 256, 0, stream>>>(xyz, bound, cursors, sxyz, N);
    // DFT pipeline
    k_stage1<<<480, 512, 0, stream>>>(Pu_re, Pu_im, Pv_re, Pv_im, Apw,
                                      alpha_params, Wre, Bfr);
    k_stage2<<<dim3(16, 10, 3), 640, 0, stream>>>(Bfr, Wre, Tall);
    // sampler
    k_sample<<<(N + 15) / 16, 256, 0, stream>>>(sxyz, Tu, Tv, Tw, out, N);
}

// Round 10
// 259.256 us; speedup vs baseline: 1.0861x; 1.0861x over previous
//
#include <hip/hip_runtime.h>
#include <hip/hip_bf16.h>

#define G 160
#define GM1 159
#define KD 128    // 16 k * 8 d complex channels
#define KP 320    // doubled K (re/im interleaved)
#define PLANE_U 3276800   // uints per plane of B/T (128*160*160)
#define NBUCK 4096        // 2^12 morton buckets (4 bits/axis)
#define TWO_PI_F 6.28318530717958647692f

typedef __attribute__((ext_vector_type(8))) short bf16x8;   // 4 VGPRs, 8 bf16
typedef __attribute__((ext_vector_type(4))) float f32x4;

__device__ __forceinline__ unsigned short f2bf(float x) {
    unsigned u = __float_as_uint(x);
    unsigned r = (u + 0x7FFFu + ((u >> 16) & 1u)) >> 16;   // RNE
    return (unsigned short)r;
}
__device__ __forceinline__ unsigned int packbf(float re, float im) {
    union { __hip_bfloat162 h; unsigned int u; } cv;
    cv.h = __float22bfloat162_rn(make_float2(re, im));      // v_cvt_pk_bf16_f32
    return cv.u;
}
__device__ __forceinline__ float bfl(unsigned u) { return __uint_as_float(u << 16); }
__device__ __forceinline__ float bfh(unsigned u) { return __uint_as_float(u & 0xffff0000u); }
// Wim fragment uint from Wre fragment uint: (c,-s) -> (s,c)
__device__ __forceinline__ unsigned int wim_of(unsigned int u) {
    return ((u << 16) | (u >> 16)) ^ 0x00008000u;
}
__device__ __forceinline__ unsigned part1by2(unsigned x) {
    x &= 0x3FF;
    x = (x | (x << 16)) & 0xFF0000FFu;
    x = (x | (x << 8))  & 0x0300F00Fu;
    x = (x | (x << 4))  & 0x030C30C3u;
    x = (x | (x << 2))  & 0x09249249u;
    return x;
}
__device__ __forceinline__ unsigned morton_key(float x, float y, float z) {
    int cx = min(max((int)((x + 1.0f) * 8.0f), 0), 15);
    int cy = min(max((int)((y + 1.0f) * 8.0f), 0), 15);
    int cz = min(max((int)((z + 1.0f) * 8.0f), 0), 15);
    return part1by2(cx) | (part1by2(cy) << 1) | (part1by2(cz) << 2);   // 12 bits
}

// ---------------------------------------------------------------------------
// Fused preprocessing: [0,16) zero counts | [16,216) W init | [216,1816) packw
// ---------------------------------------------------------------------------
__global__ __launch_bounds__(256) void k_prep(
    const float* __restrict__ Pw_re, const float* __restrict__ Pw_im,
    unsigned int* __restrict__ Apw, unsigned short* __restrict__ Wre,
    unsigned int* __restrict__ counts)
{
    __shared__ unsigned int sT[64 * 33];
    int b = blockIdx.x;
    int tid = threadIdx.x;
    if (b < 16) {
        counts[b * 256 + tid] = 0;
        return;
    }
    if (b < 216) {
        int idx = (b - 16) * 256 + tid;   // < 51200
        int r = idx / KP, kp = idx - r * KP;
        int q = kp >> 1;
        int m = (r * q) % G;
        float th = (float)m * (TWO_PI_F / (float)G);
        float s, c;
        __sincosf(th, &s, &c);
        Wre[idx] = f2bf(((kp & 1) == 0 ? c : -s) * (1.0f / (float)G));
        return;
    }
    // packw: Pw (k,y,x,d) [204800, 8, 1280, 1] -> Apw[m=(k*8+d)*160+y][q=x]
    int b2 = b - 216;                     // 0..1599
    int k  = b2 / 100;
    int rem = b2 - k * 100;
    int pc = rem / 5;
    int q0 = (rem - pc * 5) * 32;

    int i = tid & 63, qo = tid >> 6;
    size_t base = (size_t)k * 204800 + (size_t)pc * 64 + i;
    #pragma unroll
    for (int qc = 0; qc < 8; qc++) {
        int q = q0 + qo * 8 + qc;
        float r  = Pw_re[base + (size_t)q * 1280];
        float im = Pw_im[base + (size_t)q * 1280];
        sT[i * 33 + qo * 8 + qc] = packbf(r, im);
    }
    __syncthreads();
    int qp = tid & 31, mo = tid >> 5;
    #pragma unroll
    for (int mc = 0; mc < 8; mc++) {
        int m = (k * 8 + mo) * G + pc * 8 + mc;
        Apw[(size_t)m * G + q0 + qp] = sT[(mc * 8 + mo) * 33 + qp];
    }
}

// ---------------------------------------------------------------------------
// Morton counting sort: hist -> scan -> scatter(sorted float4)
// ---------------------------------------------------------------------------
__global__ __launch_bounds__(256) void k_hist(
    const float* __restrict__ xyz, const float* __restrict__ bound,
    unsigned int* __restrict__ counts, int N)
{
    int i = blockIdx.x * blockDim.x + threadIdx.x;
    if (i >= N) return;
    float invb = 1.0f / bound[0];
    float x = xyz[3 * i + 0] * invb;
    float y = xyz[3 * i + 1] * invb;
    float z = xyz[3 * i + 2] * invb;
    atomicAdd(&counts[morton_key(x, y, z)], 1u);
}

__global__ __launch_bounds__(1024) void k_scan(
    const unsigned int* __restrict__ counts,
    unsigned int* __restrict__ cursors)
{
    __shared__ unsigned int sT[1024];
    int t = threadIdx.x;
    unsigned int local[4];
    unsigned int s = 0;
    #pragma unroll
    for (int i = 0; i < 4; i++) { local[i] = counts[t * 4 + i]; s += local[i]; }
    sT[t] = s;
    __syncthreads();
    for (int off = 1; off < 1024; off <<= 1) {
        unsigned int v = (t >= off) ? sT[t - off] : 0u;
        __syncthreads();
        sT[t] += v;
        __syncthreads();
    }
    unsigned int run = (t > 0) ? sT[t - 1] : 0u;
    #pragma unroll
    for (int i = 0; i < 4; i++) { cursors[t * 4 + i] = run; run += local[i]; }
}

__global__ __launch_bounds__(256) void k_scatter(
    const float* __restrict__ xyz, const float* __restrict__ bound,
    unsigned int* __restrict__ cursors, float4* __restrict__ sxyz, int N)
{
    int i = blockIdx.x * blockDim.x + threadIdx.x;
    if (i >= N) return;
    float invb = 1.0f / bound[0];
    float x = xyz[3 * i + 0] * invb;
    float y = xyz[3 * i + 1] * invb;
    float z = xyz[3 * i + 2] * invb;
    unsigned int pos = atomicAdd(&cursors[morton_key(x, y, z)], 1u);
    sxyz[pos] = make_float4(x, y, z, __int_as_float(i));
}

// ---------------------------------------------------------------------------
// Stage 1: B[m=(kd,p)][l] = alpha * sum_q A*W[l][q].  Wave = 2 m-tiles
// (A-frags in registers, 4 MFMA per W load) x 2 l-tiles per t-step
// (2 W streams, 8 independent MFMA chains to cover load+MFMA latency).
// Output in MFMA B-frag order.
// ---------------------------------------------------------------------------
__global__ __launch_bounds__(512) void k_stage1(
    const float* __restrict__ Pu_re, const float* __restrict__ Pu_im,
    const float* __restrict__ Pv_re, const float* __restrict__ Pv_im,
    const unsigned int* __restrict__ Apw,
    const float* __restrict__ alpha_params,
    const unsigned short* __restrict__ Wre,
    unsigned int* __restrict__ Bfrag)
{
    int tid = threadIdx.x;
    int w = tid >> 6, lane = tid & 63;
    int col = lane & 15, g4 = lane >> 4;
    int gw = blockIdx.x * 8 + w;          // 0..1919 wave-tasks
    int mt0 = gw * 2;                     // global m-tile pair
    int plane = mt0 / 1280;
    int mtl0 = mt0 - plane * 1280;        // plane-local tile idx (even)

    float ap = alpha_params[0];
    float bxv = 10.0f * ap;
    float alpha = (bxv > 1.0f) ? ap : log1pf(expf(fminf(bxv, 1.0f))) * 0.1f;

    bf16x8 afr[2][10];
    #pragma unroll
    for (int ti = 0; ti < 2; ti++) {
        int mtl = mtl0 + ti;
        if (plane == 2) {
            const unsigned int* a2 = Apw + (size_t)(mtl * 16 + col) * G + g4 * 4;
            #pragma unroll
            for (int t = 0; t < 10; t++) {
                union { uint4 u; bf16x8 b; } cv;
                cv.u = *(const uint4*)(a2 + t * 16);
                afr[ti][t] = cv.b;
            }
        } else {
            const float *Ar, *Ai; int sd_, sp_;
            if (plane == 0) { Ar = Pu_re; Ai = Pu_im; sd_ = 25600; sp_ = 160; }
            else            { Ar = Pv_re; Ai = Pv_im; sd_ = 160;   sp_ = 1280; }
            int m = mtl * 16 + col;
            int k = m / 1280; int rm = m - k * 1280;
            int d = rm / 160; int p = rm - d * 160;
            size_t abase = (size_t)k * 204800 + (size_t)d * sd_ + (size_t)p * sp_ + g4 * 4;
            #pragma unroll
            for (int t = 0; t < 10; t++) {
                float4 vr = *(const float4*)(Ar + abase + t * 16);
                float4 vi = *(const float4*)(Ai + abase + t * 16);
                union { unsigned int u[4]; bf16x8 b; } cv;
                cv.u[0] = packbf(vr.x, vi.x); cv.u[1] = packbf(vr.y, vi.y);
                cv.u[2] = packbf(vr.z, vi.z); cv.u[3] = packbf(vr.w, vi.w);
                afr[ti][t] = cv.b;
            }
        }
    }

    unsigned int* Bpl = Bfrag + (size_t)plane * PLANE_U;
    int kd0 = mtl0 / 10, pt0 = mtl0 - kd0 * 10;
    int mtl1 = mtl0 + 1;
    int kd1 = mtl1 / 10, pt1 = mtl1 - kd1 * 10;

    for (int lt2 = 0; lt2 < 5; lt2++) {
        int ltA = lt2 * 2, ltB = lt2 * 2 + 1;
        // acc[tile][lt-half] re/im — 8 independent MFMA chains
        f32x4 arA0 = (f32x4)(0.f), aiA0 = (f32x4)(0.f);
        f32x4 arA1 = (f32x4)(0.f), aiA1 = (f32x4)(0.f);
        f32x4 arB0 = (f32x4)(0.f), aiB0 = (f32x4)(0.f);
        f32x4 arB1 = (f32x4)(0.f), aiB1 = (f32x4)(0.f);
        const unsigned short* wpA = &Wre[(ltA * 16 + col) * KP + g4 * 8];
        const unsigned short* wpB = &Wre[(ltB * 16 + col) * KP + g4 * 8];
        #pragma unroll
        for (int t = 0; t < 10; t++) {
            union { uint4 u; bf16x8 b; } crA, ciA, crB, ciB;
            crA.u = *(const uint4*)(wpA + t * 32);
            crB.u = *(const uint4*)(wpB + t * 32);
            ciA.u.x = wim_of(crA.u.x); ciA.u.y = wim_of(crA.u.y);
            ciA.u.z = wim_of(crA.u.z); ciA.u.w = wim_of(crA.u.w);
            ciB.u.x = wim_of(crB.u.x); ciB.u.y = wim_of(crB.u.y);
            ciB.u.z = wim_of(crB.u.z); ciB.u.w = wim_of(crB.u.w);
            arA0 = __builtin_amdgcn_mfma_f32_16x16x32_bf16(afr[0][t], crA.b, arA0, 0, 0, 0);
            aiA0 = __builtin_amdgcn_mfma_f32_16x16x32_bf16(afr[0][t], ciA.b, aiA0, 0, 0, 0);
            arB0 = __builtin_amdgcn_mfma_f32_16x16x32_bf16(afr[0][t], crB.b, arB0, 0, 0, 0);
            aiB0 = __builtin_amdgcn_mfma_f32_16x16x32_bf16(afr[0][t], ciB.b, aiB0, 0, 0, 0);
            arA1 = __builtin_amdgcn_mfma_f32_16x16x32_bf16(afr[1][t], crA.b, arA1, 0, 0, 0);
            aiA1 = __builtin_amdgcn_mfma_f32_16x16x32_bf16(afr[1][t], ciA.b, aiA1, 0, 0, 0);
            arB1 = __builtin_amdgcn_mfma_f32_16x16x32_bf16(afr[1][t], crB.b, arB1, 0, 0, 0);
            aiB1 = __builtin_amdgcn_mfma_f32_16x16x32_bf16(afr[1][t], ciB.b, aiB1, 0, 0, 0);
        }
        uint4 o;
        o.x = packbf(alpha * arA0[0], alpha * aiA0[0]);
        o.y = packbf(alpha * arA0[1], alpha * aiA0[1]);
        o.z = packbf(alpha * arA0[2], alpha * aiA0[2]);
        o.w = packbf(alpha * arA0[3], alpha * aiA0[3]);
        *(uint4*)(Bpl + (size_t)(kd0 * 10 + ltA) * 2560 + pt0 * 256 + lane * 4) = o;
        o.x = packbf(alpha * arB0[0], alpha * aiB0[0]);
        o.y = packbf(alpha * arB0[1], alpha * aiB0[1]);
        o.z = packbf(alpha * arB0[2], alpha * aiB0[2]);
        o.w = packbf(alpha * arB0[3], alpha * aiB0[3]);
        *(uint4*)(Bpl + (size_t)(kd0 * 10 + ltB) * 2560 + pt0 * 256 + lane * 4) = o;
        o.x = packbf(alpha * arA1[0], alpha * aiA1[0]);
        o.y = packbf(alpha * arA1[1], alpha * aiA1[1]);
        o.z = packbf(alpha * arA1[2], alpha * aiA1[2]);
        o.w = packbf(alpha * arA1[3], alpha * aiA1[3]);
        *(uint4*)(Bpl + (size_t)(kd1 * 10 + ltA) * 2560 + pt1 * 256 + lane * 4) = o;
        o.x = packbf(alpha * arB1[0], alpha * aiB1[0]);
        o.y = packbf(alpha * arB1[1], alpha * aiB1[1]);
        o.z = packbf(alpha * arB1[2], alpha * aiB1[2]);
        o.w = packbf(alpha * arB1[3], alpha * aiB1[3]);
        *(uint4*)(Bpl + (size_t)(kd1 * 10 + ltB) * 2560 + pt1 * 256 + lane * 4) = o;
    }
}

// ---------------------------------------------------------------------------
// Stage 2: T[j][l][kd] = sum_p W[j][p]*B[kd][p][l].
// Block = (kd-octet, l-tile, plane), 640 thr = 10 waves = 10 j-tiles.
// B octet staged once into 80KB LDS; W A-frags register-hoisted.
// ---------------------------------------------------------------------------
__global__ __launch_bounds__(640) void k_stage2(
    const unsigned int* __restrict__ Bfrag,
    const unsigned short* __restrict__ Wre,
    unsigned int* __restrict__ Tall)
{
    __shared__ __align__(16) unsigned int sB[20480];   // 80 KB: 8 kd x 2560
    int tid = threadIdx.x;
    int w = tid >> 6, lane = tid & 63;
    int col = lane & 15, g4 = lane >> 4;
    int kdo = blockIdx.x;
    int lt  = blockIdx.y;
    int plane = blockIdx.z;

    const unsigned int* Bp = Bfrag + (size_t)plane * PLANE_U;
    #pragma unroll
    for (int i = 0; i < 8; i++) {
        uint4 v = *(const uint4*)(Bp + ((size_t)(kdo * 8 + i) * 10 + lt) * 2560 + tid * 4);
        *(uint4*)(sB + i * 2560 + tid * 4) = v;
    }

    bf16x8 wfr[10];
    const unsigned short* wp = &Wre[(w * 16 + col) * KP + g4 * 8];
    #pragma unroll
    for (int t = 0; t < 10; t++)
        wfr[t] = *(const bf16x8*)(wp + t * 32);

    __syncthreads();

    f32x4 ar[8], ai[8];
    #pragma unroll
    for (int i = 0; i < 8; i++) { ar[i] = (f32x4)(0.f); ai[i] = (f32x4)(0.f); }

    #pragma unroll
    for (int t = 0; t < 10; t++) {
        union { bf16x8 b; uint4 u; } cr, ci;
        cr.b = wfr[t];
        ci.u.x = wim_of(cr.u.x); ci.u.y = wim_of(cr.u.y);
        ci.u.z = wim_of(cr.u.z); ci.u.w = wim_of(cr.u.w);
        #pragma unroll
        for (int kq = 0; kq < 8; kq++) {
            bf16x8 bf = *(const bf16x8*)&sB[kq * 2560 + (t * 64 + lane) * 4];
            ar[kq] = __builtin_amdgcn_mfma_f32_16x16x32_bf16(cr.b, bf, ar[kq], 0, 0, 0);
            ai[kq] = __builtin_amdgcn_mfma_f32_16x16x32_bf16(ci.b, bf, ai[kq], 0, 0, 0);
        }
    }

    unsigned int* Tp = Tall + (size_t)plane * PLANE_U;
    #pragma unroll
    for (int reg = 0; reg < 4; reg++) {
        int j = w * 16 + g4 * 4 + reg;
        int l = lt * 16 + col;
        uint4 o0, o1;
        o0.x = packbf(ar[0][reg], ai[0][reg]);
        o0.y = packbf(ar[1][reg], ai[1][reg]);
        o0.z = packbf(ar[2][reg], ai[2][reg]);
        o0.w = packbf(ar[3][reg], ai[3][reg]);
        o1.x = packbf(ar[4][reg], ai[4][reg]);
        o1.y = packbf(ar[5][reg], ai[5][reg]);
        o1.z = packbf(ar[6][reg], ai[6][reg]);
        o1.w = packbf(ar[7][reg], ai[7][reg]);
        size_t ta = ((size_t)(j * G + l)) * KD + kdo * 8;
        *(uint4*)(Tp + ta)     = o0;
        *(uint4*)(Tp + ta + 4) = o1;
    }
}

// ---------------------------------------------------------------------------
// Sampler: 16 lanes/point, lane = k. Phase-split: all 3 planes' addresses,
// all 24 uint4 loads in flight, then f32 unpack math (PROVEN R7 path).
// ---------------------------------------------------------------------------
__device__ __forceinline__ void plane_addr(const unsigned int* __restrict__ T,
    float gy, float gx, int k, const unsigned int** cp, float* wv)
{
    float iy = (gy + 1.0f) * (0.5f * (float)GM1);
    float ix = (gx + 1.0f) * (0.5f * (float)GM1);
    float iy0f = floorf(iy), ix0f = floorf(ix);
    float wy = iy - iy0f, wx = ix - ix0f;
    int iy0 = (int)iy0f, ix0 = (int)ix0f;
    int iy1 = min(iy0 + 1, GM1), ix1 = min(ix0 + 1, GM1);
    iy0 = max(min(iy0, GM1), 0); ix0 = max(min(ix0, GM1), 0);
    iy1 = max(iy1, 0); ix1 = max(ix1, 0);
    cp[0] = &T[(size_t)(iy0 * G + ix0) * KD + k * 8];
    cp[1] = &T[(size_t)(iy0 * G + ix1) * KD + k * 8];
    cp[2] = &T[(size_t)(iy1 * G + ix0) * KD + k * 8];
    cp[3] = &T[(size_t)(iy1 * G + ix1) * KD + k * 8];
    wv[0] = (1.f - wx) * (1.f - wy);
    wv[1] = wx * (1.f - wy);
    wv[2] = (1.f - wx) * wy;
    wv[3] = wx * wy;
}

__device__ __forceinline__ float plane_math(const uint4* va, const uint4* vb,
                                            const float* wv, float fc)
{
    float w00 = wv[0], w01 = wv[1], w10 = wv[2], w11 = wv[3];
    float s1v, c1v;
    __sincosf(TWO_PI_F * fc, &s1v, &c1v);
    float cd[8], sd[8];
    cd[1] = c1v; sd[1] = s1v;
    #pragma unroll
    for (int d = 2; d < 8; d++) {
        float t2 = cd[d - 1] + cd[d - 1];
        cd[d] = __builtin_fmaf(t2, cd[d - 1], -1.0f);
        sd[d] = t2 * sd[d - 1];
    }
    float acc = 0.f;
#define TERM(u0, u1, u2, u3, C, S) { \
    float re = bfl(u0) * w00 + bfl(u1) * w01 + bfl(u2) * w10 + bfl(u3) * w11; \
    float im = bfh(u0) * w00 + bfh(u1) * w01 + bfh(u2) * w10 + bfh(u3) * w11; \
    acc += re * (C) - im * (S); }
    TERM(va[0].x, va[1].x, va[2].x, va[3].x, 1.0f, 0.0f)
    TERM(va[0].y, va[1].y, va[2].y, va[3].y, cd[1] + cd[1], sd[1] + sd[1])
    TERM(va[0].z, va[1].z, va[2].z, va[3].z, cd[2] + cd[2], sd[2] + sd[2])
    TERM(va[0].w, va[1].w, va[2].w, va[3].w, cd[3] + cd[3], sd[3] + sd[3])
    TERM(vb[0].x, vb[1].x, vb[2].x, vb[3].x, cd[4] + cd[4], sd[4] + sd[4])
    TERM(vb[0].y, vb[1].y, vb[2].y, vb[3].y, cd[5] + cd[5], sd[5] + sd[5])
    TERM(vb[0].z, vb[1].z, vb[2].z, vb[3].z, cd[6] + cd[6], sd[6] + sd[6])
    TERM(vb[0].w, vb[1].w, vb[2].w, vb[3].w, cd[7] + cd[7], sd[7] + sd[7])
#undef TERM
    return acc;
}

__global__ __launch_bounds__(256, 3) void k_sample(
    const float4* __restrict__ sxyz,
    const unsigned int* __restrict__ Tu, const unsigned int* __restrict__ Tv,
    const unsigned int* __restrict__ Tw,
    float* __restrict__ out, int N)
{
    int tid = threadIdx.x;
    int k = tid & 15;
    int nblocks = (N + 15) / 16;
    int seg = blockIdx.x & 7;
    int segblocks = nblocks >> 3;                 // N multiple of 128
    int pid = (seg * segblocks + (blockIdx.x >> 3)) * 16 + (tid >> 4);
    if (pid >= N) return;

    float4 pw = sxyz[pid];
    int n = __float_as_int(pw.w);
    float x = pw.x, y = pw.y, z = pw.z;

    const unsigned int* cp[3][4];
    float wv[3][4];
    plane_addr(Tu, y, z, k, cp[0], wv[0]);
    plane_addr(Tv, x, z, k, cp[1], wv[1]);
    plane_addr(Tw, y, x, k, cp[2], wv[2]);

    uint4 va[3][4], vb[3][4];
    #pragma unroll
    for (int pl = 0; pl < 3; pl++)
        #pragma unroll
        for (int c = 0; c < 4; c++) {
            va[pl][c] = *(const uint4*)cp[pl][c];
            vb[pl][c] = *(const uint4*)(cp[pl][c] + 4);
        }

    float acc = plane_math(va[0], vb[0], wv[0], (x + 1.0f) * 0.5f)
              + plane_math(va[1], vb[1], wv[1], (y + 1.0f) * 0.5f)
              + plane_math(va[2], vb[2], wv[2], (z + 1.0f) * 0.5f);
    out[n * 16 + k] = acc;
}

// ---------------------------------------------------------------------------
extern "C" void kernel_launch(void* const* d_in, const int* in_sizes, int n_in,
                              void* d_out, int out_size, void* d_ws, size_t ws_size,
                              hipStream_t stream) {
    const float* xyz          = (const float*)d_in[0];
    const float* bound        = (const float*)d_in[1];
    const float* alpha_params = (const float*)d_in[2];
    const float* Pu_re = (const float*)d_in[3];
    const float* Pu_im = (const float*)d_in[4];
    const float* Pv_re = (const float*)d_in[5];
    const float* Pv_im = (const float*)d_in[6];
    const float* Pw_re = (const float*)d_in[7];
    const float* Pw_im = (const float*)d_in[8];
    float* out = (float*)d_out;
    int N = in_sizes[0] / 3;

    // ws: Wre 100K | Apw 12.5M | Bfrag 37.5M | T 37.5M | counts 16K |
    //     cursors 16K | sxyz 2M
    char* ws = (char*)d_ws;
    unsigned short* Wre  = (unsigned short*)(ws);
    unsigned int*   Apw  = (unsigned int*)(ws + 102400);
    unsigned int*   Bfr  = (unsigned int*)(ws + 102400 + 13107200);
    unsigned int*   Tall = (unsigned int*)(ws + 102400 + 13107200 + 39321600);
    char*           ws2  = ws + 102400 + 13107200 + 39321600 + 39321600;
    unsigned int*   counts  = (unsigned int*)(ws2);
    unsigned int*   cursors = (unsigned int*)(ws2 + 16384);
    float4*         sxyz    = (float4*)(ws2 + 32768);
    unsigned int*   Tu   = Tall;
    unsigned int*   Tv   = Tall + (size_t)PLANE_U;
    unsigned int*   Tw   = Tall + (size_t)2 * PLANE_U;

    // fused prep: zero counts + W table + Pw pack
    k_prep<<<1816, 256, 0, stream>>>(Pw_re, Pw_im, Apw, Wre, counts);
    // sort chain
    k_hist<<<(N + 255) / 256, 256, 0, stream>>>(xyz, bound, counts, N);
    k_scan<<<1, 1024, 0, stream>>>(counts, cursors);
    k_scatter<<<(N + 255) / 256, 256, 0, stream>>>(xyz, bound, cursors, sxyz, N);
    // DFT pipeline
    k_stage1<<<240, 512, 0, stream>>>(Pu_re, Pu_im, Pv_re, Pv_im, Apw,
                                      alpha_params, Wre, Bfr);
    k_stage2<<<dim3(16, 10, 3), 640, 0, stream>>>(Bfr, Wre, Tall);
    // sampler
    k_sample<<<(N + 15) / 16, 256, 0, stream>>>(sxyz, Tu, Tv, Tw, out, N);
}